// Round 6
// baseline (91.369 us; speedup 1.0000x reference)
//
#include <hip/hip_runtime.h>
#include <hip/hip_bf16.h>

#define NFFT    1024
#define HOPSZ   256
#define XLEN    262144
#define PADLEN  (XLEN + NFFT)      // 263168
#define NBATCH  16
#define NBINS2  1026
#define FBIN    513
#define NFRAMES 1025
#define NGF     (NBATCH * NFRAMES) // 16400
#define TOTOUT  ((size_t)NBATCH * FBIN * NFRAMES)

// GEMM geometry: BM=256 x BN=256, BK=64, 8 waves (2M x 4N), per-wave 128x64
#define KT 64
#define NKT 16
#define NT_TILES 64
#define MT_TILES 4
#define NWG (MT_TILES * NT_TILES)  // 256
#define ABYTES 32768               // A region bytes per buffer
#define BUFE   32768               // elems per buffer
#define BUFB   65536               // bytes per buffer
#define NTAIL  49184               // 2*16400 + 16*1024

typedef short bf16x8 __attribute__((ext_vector_type(8)));
typedef float f32x4  __attribute__((ext_vector_type(4)));
typedef unsigned short u16x8 __attribute__((ext_vector_type(8)));
typedef unsigned short u16x4 __attribute__((ext_vector_type(4)));

__device__ __forceinline__ unsigned short f2bf(float f) {
  union { float f; unsigned u; } v; v.f = f;
  unsigned r = v.u + 0x7fffu + ((v.u >> 16) & 1u);   // RNE
  return (unsigned short)(r >> 16);
}
__device__ __forceinline__ float bf2f(unsigned short h) {
  union { unsigned u; float f; } v; v.u = ((unsigned)h) << 16; return v.f;
}

typedef __attribute__((address_space(1))) void void_g;
typedef __attribute__((address_space(3))) void void_l;
__device__ __forceinline__ void gload_lds16(const void* g, void* l) {
  __builtin_amdgcn_global_load_lds((void_g*)(g), (void_l*)(l), 16, 0, 0);
}

// ---- pack x -> bf16 with center padding ----
__global__ __launch_bounds__(256) void pack_x_kernel(const float* __restrict__ x,
                                                     unsigned short* __restrict__ xp) {
  long long t = (long long)blockIdx.x * 256 + threadIdx.x;
  long long base = t * 8;
  if (base >= (long long)NBATCH * PADLEN) return;
  int b   = (int)(base / PADLEN);
  int pos = (int)(base % PADLEN);
  const float* xb = x + (long long)b * XLEN;
  u16x8 v;
#pragma unroll
  for (int j = 0; j < 8; ++j) {
    int xi = pos + j - (NFFT / 2);
    float f = ((unsigned)xi < (unsigned)XLEN) ? xb[xi] : 0.0f;
    v[j] = f2bf(f);
  }
  *reinterpret_cast<u16x8*>(xp + base) = v;
}

// ---- pack W -> bf16 ----
__global__ __launch_bounds__(256) void pack_w_kernel(const float* __restrict__ W,
                                                     unsigned short* __restrict__ Wb) {
  long long t = ((long long)blockIdx.x * 256 + threadIdx.x) * 4;
  if (t >= (long long)NBINS2 * NFFT) return;
  float4 f = *reinterpret_cast<const float4*>(W + t);
  u16x4 v;
  v[0] = f2bf(f.x); v[1] = f2bf(f.y); v[2] = f2bf(f.z); v[3] = f2bf(f.w);
  *reinterpret_cast<u16x4*>(Wb + t) = v;
}

// ---- 256x256 GEMM, m201-style 4-phase schedule, counted vmcnt (never 0 in
//      steady state), piece-granular staging, T2 swizzle, fused tail ----
__global__ __launch_bounds__(512, 2) void stft_mfma8_kernel(const unsigned short* __restrict__ Xp,
                                                            const unsigned short* __restrict__ Wb,
                                                            float* __restrict__ out) {
  extern __shared__ unsigned short lds[];   // 2 x 64 KiB
  const int tid = threadIdx.x;
  const int l   = tid & 63;
  const int w   = tid >> 6;        // 0..7
  const int wr  = w >> 2;          // M half (128 rows)
  const int wc  = w & 3;           // N quarter (64 cols)
  const int r16 = l & 15, hi = l >> 4;

  // XCD swizzle
  const int bid = blockIdx.x;
  const int c_  = bid >> 3;
  const int nt  = (bid & 7) * 8 + (c_ & 7);
  const int mt  = c_ >> 3;
  const int bin0 = mt * 256;
  const int gf0  = nt * 256;

  // staging addresses (pre-swizzled global source)
  const int lr = l >> 3;
  const int ls = l & 7;
  const int cswz = ((ls ^ lr) << 3);

  // A quarter-pieces: Q qi = rows [qi*64, qi*64+64); 1 load/thread/quarter
  unsigned aqoff[4];
#pragma unroll
  for (int qi = 0; qi < 4; ++qi)
    aqoff[qi] = (unsigned)(bin0 + qi * 64 + w * 8 + lr) * NFFT + cswz;
  // B: full 256x64; 4 loads/thread
  unsigned boff[4];
#pragma unroll
  for (int j = 0; j < 4; ++j) {
    const int gf = gf0 + (w * 4 + j) * 8 + lr;     // < 16384
    const int bb = gf / NFRAMES;
    const int fr = gf - bb * NFRAMES;
    boff[j] = (unsigned)bb * PADLEN + (unsigned)fr * HOPSZ + cswz;
  }

#define STG_Q(D, QI, KC) gload_lds16(Wb + aqoff[QI] + (KC), lds + (D) * BUFE + (QI) * 4096 + w * 512)
#define STG_B(D, KC) do { \
    _Pragma("unroll") \
    for (int j_ = 0; j_ < 4; ++j_) \
      gload_lds16(Xp + boff[j_] + (KC), lds + (D) * BUFE + 16384 + (w * 4 + j_) * 512); \
    } while (0)

  // fragment read bases (T2 XOR-swizzle)
  const int aB0 = (wr * 128 + r16) * 128;
  const int bB0 = ABYTES + (wc * 64 + r16) * 128;
  const int swz = (r16 & 7) << 4;
  const int c0  = (hi * 16) ^ swz;
  const int c1  = (64 + hi * 16) ^ swz;

#define RD_A(BASE, MH, C) do { \
    _Pragma("unroll") \
    for (int m_ = 0; m_ < 4; ++m_) \
      Aq[m_] = *reinterpret_cast<const bf16x8*>((BASE) + aB0 + (MH) * 8192 + m_ * 2048 + (C)); \
    } while (0)
#define RD_B(BASE, C) do { \
    _Pragma("unroll") \
    for (int n_ = 0; n_ < 4; ++n_) \
      Bq[n_] = *reinterpret_cast<const bf16x8*>((BASE) + bB0 + n_ * 2048 + (C)); \
    } while (0)

#define MFMA16(MLO) do { \
    __builtin_amdgcn_s_setprio(1); \
    _Pragma("unroll") \
    for (int m_ = 0; m_ < 4; ++m_) { \
      _Pragma("unroll") \
      for (int n_ = 0; n_ < 4; ++n_) \
        acc[(MLO) + m_][n_] = __builtin_amdgcn_mfma_f32_16x16x32_bf16(Aq[m_], Bq[n_], acc[(MLO) + m_][n_], 0, 0, 0); \
    } \
    __builtin_amdgcn_s_setprio(0); } while (0)

  f32x4 acc[8][4] = {};
  bf16x8 Aq[4], Bq[4];

  // ---- prologue: kt0 complete (8), kt1 Q0,Q2,B (6); counted wait ----
  STG_Q(0, 0, 0); STG_Q(0, 1, 0); STG_Q(0, 2, 0); STG_Q(0, 3, 0); STG_B(0, 0);
  STG_Q(1, 0, KT); STG_Q(1, 2, KT); STG_B(1, KT);
  asm volatile("s_waitcnt vmcnt(6)" ::: "memory");   // kt0 landed; kt1's 6 in flight
  __builtin_amdgcn_s_barrier();
  __builtin_amdgcn_sched_barrier(0);

  for (int t = 0; t < NKT; ++t) {
    const int c = t & 1, n = c ^ 1;
    const char* base = (const char*)lds + c * BUFB;
    const int kc1 = (t + 1) << 6;
    const int kc2 = (t + 2) << 6;

    // ---- Ph0: vmcnt; reads A(m0-3,ks0)+B(ks0); bar; stage Q1,Q3(kt+1->n); MFMA ----
    if (t < NKT - 1) asm volatile("s_waitcnt vmcnt(6)" ::: "memory");
    else             asm volatile("s_waitcnt vmcnt(0)" ::: "memory");
    __builtin_amdgcn_sched_barrier(0);
    RD_A(base, 0, c0);
    RD_B(base, c0);
    __builtin_amdgcn_s_barrier();
    if (t < NKT - 1) { STG_Q(n, 1, kc1); STG_Q(n, 3, kc1); }
    asm volatile("s_waitcnt lgkmcnt(0)" ::: "memory");
    __builtin_amdgcn_sched_barrier(0);
    MFMA16(0);

    // ---- Ph1: reads A(m4-7,ks0); bar; MFMA ----
    RD_A(base, 1, c0);
    __builtin_amdgcn_s_barrier();
    asm volatile("s_waitcnt lgkmcnt(0)" ::: "memory");
    __builtin_amdgcn_sched_barrier(0);
    MFMA16(4);

    // ---- Ph2: reads A(m0-3,ks1)+B(ks1); bar; MFMA ----
    RD_A(base, 0, c1);
    RD_B(base, c1);
    __builtin_amdgcn_s_barrier();
    asm volatile("s_waitcnt lgkmcnt(0)" ::: "memory");
    __builtin_amdgcn_sched_barrier(0);
    MFMA16(0);

    // ---- Ph3: reads A(m4-7,ks1); bar; stage Q0,Q2,B(kt+2->c); MFMA ----
    RD_A(base, 1, c1);
    __builtin_amdgcn_s_barrier();
    if (t < NKT - 2) { STG_Q(c, 0, kc2); STG_Q(c, 2, kc2); STG_B(c, kc2); }
    asm volatile("s_waitcnt lgkmcnt(0)" ::: "memory");
    __builtin_amdgcn_sched_barrier(0);
    MFMA16(4);
  }

  // ---- epilogue: D row = bin, col = frame ----
  const int col   = l & 15;
  const int rbase = (l >> 4) * 4;
#pragma unroll
  for (int m = 0; m < 8; ++m) {
#pragma unroll
    for (int n2 = 0; n2 < 4; ++n2) {
      const int gf = gf0 + wc * 64 + n2 * 16 + col;
      const int bb = gf / NFRAMES;
      const int fr = gf - bb * NFRAMES;
#pragma unroll
      for (int r = 0; r < 4; ++r) {
        const int bin = bin0 + wr * 128 + m * 16 + rbase + r;
        size_t off;
        if (bin < FBIN) off = ((size_t)bb * FBIN + bin) * NFRAMES + fr;
        else            off = TOTOUT + ((size_t)bb * FBIN + (bin - FBIN)) * NFRAMES + fr;
        out[off] = acc[m][n2][r];
      }
    }
  }

  // ---- fused tail: bins 1024-1025 x all gf, bins 0..1023 x gf 16384..16399 ----
  {
    const int gtid = bid * 512 + tid;
    if (gtid < NTAIL) {
      int bin, gf;
      if (gtid < 2 * NGF) { bin = 1024 + (gtid & 1); gf = gtid >> 1; }
      else { const int s = gtid - 2 * NGF; gf = 16384 + (s & 15); bin = s >> 4; }
      const int bb = gf / NFRAMES;
      const int fr = gf - bb * NFRAMES;
      const unsigned short* xr = Xp + (size_t)bb * PADLEN + (size_t)fr * HOPSZ;
      const unsigned short* wrow = Wb + (size_t)bin * NFFT;
      float s0 = 0.f, s1 = 0.f;
      for (int k = 0; k < NFFT; k += 8) {
        u16x8 xv = *reinterpret_cast<const u16x8*>(xr + k);
        u16x8 wv = *reinterpret_cast<const u16x8*>(wrow + k);
#pragma unroll
        for (int j = 0; j < 8; j += 2) {
          s0 = fmaf(bf2f(xv[j]),     bf2f(wv[j]),     s0);
          s1 = fmaf(bf2f(xv[j + 1]), bf2f(wv[j + 1]), s1);
        }
      }
      const float s = s0 + s1;
      size_t off;
      if (bin < FBIN) off = ((size_t)bb * FBIN + bin) * NFRAMES + fr;
      else            off = TOTOUT + ((size_t)bb * FBIN + (bin - FBIN)) * NFRAMES + fr;
      out[off] = s;
    }
  }
#undef STG_Q
#undef STG_B
#undef RD_A
#undef RD_B
#undef MFMA16
}

// ---- exact f32 direct kernel: fallback only ----
__global__ void stft_direct_kernel(const float* __restrict__ x, const float* __restrict__ W,
                                   float* __restrict__ out,
                                   int bin_lo, int nbins, int fr_lo, int nframes) {
  long long total = (long long)NBATCH * nbins * nframes;
  for (long long t = (long long)blockIdx.x * blockDim.x + threadIdx.x; t < total;
       t += (long long)gridDim.x * blockDim.x) {
    int fr = fr_lo + (int)(t % nframes);
    long long q = t / nframes;
    int bin = bin_lo + (int)(q % nbins);
    int b   = (int)(q / nbins);
    const float* xb = x + (long long)b * XLEN;
    const float* wrow = W + (long long)bin * NFFT;
    float s = 0.f;
    const int base = fr * HOPSZ - (NFFT / 2);
    for (int j = 0; j < NFFT; ++j) {
      int xi = base + j;
      float xv = ((unsigned)xi < (unsigned)XLEN) ? xb[xi] : 0.f;
      s = fmaf(xv, wrow[j], s);
    }
    size_t off;
    if (bin < FBIN) off = ((size_t)b * FBIN + bin) * NFRAMES + fr;
    else            off = TOTOUT + ((size_t)b * FBIN + (bin - FBIN)) * NFRAMES + fr;
    out[off] = s;
  }
}

extern "C" void kernel_launch(void* const* d_in, const int* in_sizes, int n_in,
                              void* d_out, int out_size, void* d_ws, size_t ws_size,
                              hipStream_t stream) {
  const float* x = (const float*)d_in[0];
  const float* W = (const float*)d_in[1];
  float* out = (float*)d_out;

  const size_t xp_bytes = (size_t)NBATCH * PADLEN * sizeof(unsigned short);
  const size_t wb_bytes = (size_t)NBINS2 * NFFT * sizeof(unsigned short);

  if (ws_size >= xp_bytes + wb_bytes) {
    unsigned short* xp = (unsigned short*)d_ws;
    unsigned short* wb = (unsigned short*)((char*)d_ws + xp_bytes);

    {
      long long threads = (long long)NBATCH * PADLEN / 8;
      pack_x_kernel<<<(int)((threads + 255) / 256), 256, 0, stream>>>(x, xp);
    }
    pack_w_kernel<<<(NBINS2 * NFFT / 4 + 255) / 256, 256, 0, stream>>>(W, wb);

    stft_mfma8_kernel<<<NWG, 512, 2 * BUFB, stream>>>(xp, wb, out);
  } else {
    stft_direct_kernel<<<2048, 256, 0, stream>>>(x, W, out, 0, NBINS2, 0, NFRAMES);
  }
}

// Round 7
// 69.177 us; speedup vs baseline: 1.3208x; 1.3208x over previous
//
#include <hip/hip_runtime.h>
#include <hip/hip_bf16.h>

#define NFFT    1024
#define HOPSZ   256
#define XLEN    262144
#define PADLEN  (XLEN + NFFT)      // 263168
#define NBATCH  16
#define NBINS2  1026
#define FBIN    513
#define NFRAMES 1025
#define NGF     (NBATCH * NFRAMES) // 16400
#define TOTOUT  ((size_t)NBATCH * FBIN * NFRAMES)

// GEMM geometry: BM=256 x BN=256, BK=64, 8 waves (2M x 4N), per-wave 128x64
#define KT 64
#define NKT 16
#define NT_TILES 64
#define MT_TILES 4
#define NWG (MT_TILES * NT_TILES)  // 256
#define ABYTES 32768               // A region bytes per buffer
#define BUFE   32768               // elems per buffer
#define BUFB   65536               // bytes per buffer
#define NTAIL  49184               // 2*16400 + 16*1024 leftover outputs
#define PSTRIDE 130                // epilogue LDS patch row stride (f32)
#define LDS_BYTES (256 * PSTRIDE * 4)   // 133120 >= 2*BUFB

typedef short bf16x8 __attribute__((ext_vector_type(8)));
typedef float f32x4  __attribute__((ext_vector_type(4)));
typedef unsigned short u16x8 __attribute__((ext_vector_type(8)));
typedef unsigned short u16x4 __attribute__((ext_vector_type(4)));

__device__ __forceinline__ unsigned short f2bf(float f) {
  union { float f; unsigned u; } v; v.f = f;
  unsigned r = v.u + 0x7fffu + ((v.u >> 16) & 1u);   // RNE
  return (unsigned short)(r >> 16);
}
__device__ __forceinline__ float bf2f(unsigned short h) {
  union { unsigned u; float f; } v; v.u = ((unsigned)h) << 16; return v.f;
}

typedef __attribute__((address_space(1))) void void_g;
typedef __attribute__((address_space(3))) void void_l;
__device__ __forceinline__ void gload_lds16(const void* g, void* l) {
  __builtin_amdgcn_global_load_lds((void_g*)(g), (void_l*)(l), 16, 0, 0);
}

// ---- pack x -> bf16 with center padding ----
__global__ __launch_bounds__(256) void pack_x_kernel(const float* __restrict__ x,
                                                     unsigned short* __restrict__ xp) {
  long long t = (long long)blockIdx.x * 256 + threadIdx.x;
  long long base = t * 8;
  if (base >= (long long)NBATCH * PADLEN) return;
  int b   = (int)(base / PADLEN);
  int pos = (int)(base % PADLEN);
  const float* xb = x + (long long)b * XLEN;
  u16x8 v;
#pragma unroll
  for (int j = 0; j < 8; ++j) {
    int xi = pos + j - (NFFT / 2);
    float f = ((unsigned)xi < (unsigned)XLEN) ? xb[xi] : 0.0f;
    v[j] = f2bf(f);
  }
  *reinterpret_cast<u16x8*>(xp + base) = v;
}

// ---- pack W -> bf16 ----
__global__ __launch_bounds__(256) void pack_w_kernel(const float* __restrict__ W,
                                                     unsigned short* __restrict__ Wb) {
  long long t = ((long long)blockIdx.x * 256 + threadIdx.x) * 4;
  if (t >= (long long)NBINS2 * NFFT) return;
  float4 f = *reinterpret_cast<const float4*>(W + t);
  u16x4 v;
  v[0] = f2bf(f.x); v[1] = f2bf(f.y); v[2] = f2bf(f.z); v[3] = f2bf(f.w);
  *reinterpret_cast<u16x4*>(Wb + t) = v;
}

// ---- main GEMM: round-6 K-loop + NEW LDS-retiled streaming epilogue ----
__global__ __launch_bounds__(512, 2) void stft_mfma8_kernel(const unsigned short* __restrict__ Xp,
                                                            const unsigned short* __restrict__ Wb,
                                                            float* __restrict__ out) {
  extern __shared__ unsigned short lds[];   // LDS_BYTES
  const int tid = threadIdx.x;
  const int l   = tid & 63;
  const int w   = tid >> 6;        // 0..7
  const int wr  = w >> 2;          // M half (128 rows)
  const int wc  = w & 3;           // N quarter (64 cols)
  const int r16 = l & 15, hi = l >> 4;

  // XCD swizzle
  const int bid = blockIdx.x;
  const int c_  = bid >> 3;
  const int nt  = (bid & 7) * 8 + (c_ & 7);
  const int mt  = c_ >> 3;
  const int bin0 = mt * 256;
  const int gf0  = nt * 256;

  // staging addresses (pre-swizzled global source)
  const int lr = l >> 3;
  const int ls = l & 7;
  const int cswz = ((ls ^ lr) << 3);

  unsigned aqoff[4];
#pragma unroll
  for (int qi = 0; qi < 4; ++qi)
    aqoff[qi] = (unsigned)(bin0 + qi * 64 + w * 8 + lr) * NFFT + cswz;
  unsigned boff[4];
#pragma unroll
  for (int j = 0; j < 4; ++j) {
    const int gf = gf0 + (w * 4 + j) * 8 + lr;     // < 16384
    const int bb = gf / NFRAMES;
    const int fr = gf - bb * NFRAMES;
    boff[j] = (unsigned)bb * PADLEN + (unsigned)fr * HOPSZ + cswz;
  }

#define STG_Q(D, QI, KC) gload_lds16(Wb + aqoff[QI] + (KC), lds + (D) * BUFE + (QI) * 4096 + w * 512)
#define STG_B(D, KC) do { \
    _Pragma("unroll") \
    for (int j_ = 0; j_ < 4; ++j_) \
      gload_lds16(Xp + boff[j_] + (KC), lds + (D) * BUFE + 16384 + (w * 4 + j_) * 512); \
    } while (0)

  const int aB0 = (wr * 128 + r16) * 128;
  const int bB0 = ABYTES + (wc * 64 + r16) * 128;
  const int swz = (r16 & 7) << 4;
  const int c0  = (hi * 16) ^ swz;
  const int c1  = (64 + hi * 16) ^ swz;

#define RD_A(BASE, MH, C) do { \
    _Pragma("unroll") \
    for (int m_ = 0; m_ < 4; ++m_) \
      Aq[m_] = *reinterpret_cast<const bf16x8*>((BASE) + aB0 + (MH) * 8192 + m_ * 2048 + (C)); \
    } while (0)
#define RD_B(BASE, C) do { \
    _Pragma("unroll") \
    for (int n_ = 0; n_ < 4; ++n_) \
      Bq[n_] = *reinterpret_cast<const bf16x8*>((BASE) + bB0 + n_ * 2048 + (C)); \
    } while (0)

#define MFMA16(MLO) do { \
    __builtin_amdgcn_s_setprio(1); \
    _Pragma("unroll") \
    for (int m_ = 0; m_ < 4; ++m_) { \
      _Pragma("unroll") \
      for (int n_ = 0; n_ < 4; ++n_) \
        acc[(MLO) + m_][n_] = __builtin_amdgcn_mfma_f32_16x16x32_bf16(Aq[m_], Bq[n_], acc[(MLO) + m_][n_], 0, 0, 0); \
    } \
    __builtin_amdgcn_s_setprio(0); } while (0)

  f32x4 acc[8][4] = {};
  bf16x8 Aq[4], Bq[4];

  // ---- prologue: kt0 complete (8 loads), kt1 Q0,Q2,B (6); counted wait ----
  STG_Q(0, 0, 0); STG_Q(0, 1, 0); STG_Q(0, 2, 0); STG_Q(0, 3, 0); STG_B(0, 0);
  STG_Q(1, 0, KT); STG_Q(1, 2, KT); STG_B(1, KT);
  asm volatile("s_waitcnt vmcnt(6)" ::: "memory");
  __builtin_amdgcn_s_barrier();
  __builtin_amdgcn_sched_barrier(0);

  for (int t = 0; t < NKT; ++t) {
    const int c = t & 1, n = c ^ 1;
    const char* base = (const char*)lds + c * BUFB;
    const int kc1 = (t + 1) << 6;
    const int kc2 = (t + 2) << 6;

    // Ph0
    if (t < NKT - 1) asm volatile("s_waitcnt vmcnt(6)" ::: "memory");
    else             asm volatile("s_waitcnt vmcnt(0)" ::: "memory");
    __builtin_amdgcn_sched_barrier(0);
    RD_A(base, 0, c0);
    RD_B(base, c0);
    __builtin_amdgcn_s_barrier();
    if (t < NKT - 1) { STG_Q(n, 1, kc1); STG_Q(n, 3, kc1); }
    asm volatile("s_waitcnt lgkmcnt(0)" ::: "memory");
    __builtin_amdgcn_sched_barrier(0);
    MFMA16(0);

    // Ph1
    RD_A(base, 1, c0);
    __builtin_amdgcn_s_barrier();
    asm volatile("s_waitcnt lgkmcnt(0)" ::: "memory");
    __builtin_amdgcn_sched_barrier(0);
    MFMA16(4);

    // Ph2
    RD_A(base, 0, c1);
    RD_B(base, c1);
    __builtin_amdgcn_s_barrier();
    asm volatile("s_waitcnt lgkmcnt(0)" ::: "memory");
    __builtin_amdgcn_sched_barrier(0);
    MFMA16(0);

    // Ph3
    RD_A(base, 1, c1);
    __builtin_amdgcn_s_barrier();
    if (t < NKT - 2) { STG_Q(c, 0, kc2); STG_Q(c, 2, kc2); STG_B(c, kc2); }
    asm volatile("s_waitcnt lgkmcnt(0)" ::: "memory");
    __builtin_amdgcn_sched_barrier(0);
    MFMA16(4);
  }

  // ---- NEW epilogue: LDS re-tile, frame-contiguous streaming stores ----
  // Patch = [256 bins][PSTRIDE] f32; two halves of 128 frames each.
  {
    float* patch = (float*)lds;
    const int col     = l & 15;
    const int rbase   = (l >> 4) * 4;
    const int h_mine  = wc >> 1;          // which frame-half my acc lives in
    const int colbase = (wc & 1) * 64;    // col offset within that half

#pragma unroll
    for (int h = 0; h < 2; ++h) {
      __builtin_amdgcn_s_barrier();       // LDS free (K-loop reads / prev half done)
      if (h_mine == h) {
#pragma unroll
        for (int m = 0; m < 8; ++m)
#pragma unroll
          for (int n2 = 0; n2 < 4; ++n2)
#pragma unroll
            for (int r = 0; r < 4; ++r)
              patch[(wr * 128 + m * 16 + rbase + r) * PSTRIDE + colbase + n2 * 16 + col] =
                  acc[m][n2][r];
      }
      __builtin_amdgcn_s_barrier();

      // stream: wave w handles rows w, w+8, ...; per row two 256B-contiguous stores
      size_t baseR[2];
      int cols[2];
#pragma unroll
      for (int j = 0; j < 2; ++j) {
        const int gf = gf0 + h * 128 + j * 64 + l;
        const int bb = gf / NFRAMES;
        const int fr = gf - bb * NFRAMES;
        baseR[j] = (size_t)bb * FBIN * NFRAMES + fr;
        cols[j]  = h * 128 + j * 64 + l;
      }
      for (int i = 0; i < 32; ++i) {
        const int row = i * 8 + w;
        const int bin = bin0 + row;
        const size_t binoff = (size_t)bin * NFRAMES;
#pragma unroll
        for (int j = 0; j < 2; ++j) {
          const float v = patch[row * PSTRIDE + cols[j] - h * 128];
          size_t off = binoff + (bin < FBIN ? baseR[j]
                                            : baseR[j] + TOTOUT - (size_t)FBIN * NFRAMES);
          out[off] = v;
        }
      }
    }
  }
#undef STG_Q
#undef STG_B
#undef RD_A
#undef RD_B
#undef MFMA16
}

// ---- tail kernel: wave-per-output for leftover bins/frames ----
// outputs: bin in {1024,1025} x gf 0..16399, and bin 0..1023 x gf 16384..16399
__global__ __launch_bounds__(512) void stft_tail_kernel(const unsigned short* __restrict__ Xp,
                                                        const unsigned short* __restrict__ Wb,
                                                        float* __restrict__ out) {
  const int wid = (int)((blockIdx.x * 512 + threadIdx.x) >> 6);
  const int l   = threadIdx.x & 63;
  if (wid >= NTAIL) return;
  int bin, gf;
  if (wid < 2 * NGF) { bin = 1024 + (wid & 1); gf = wid >> 1; }
  else { const int s = wid - 2 * NGF; gf = 16384 + (s & 15); bin = s >> 4; }
  const int bb = gf / NFRAMES;
  const int fr = gf - bb * NFRAMES;
  const unsigned short* xr = Xp + (size_t)bb * PADLEN + (size_t)fr * HOPSZ + l * 16;
  const unsigned short* wr = Wb + (size_t)bin * NFFT + l * 16;
  u16x8 x0 = *reinterpret_cast<const u16x8*>(xr);
  u16x8 x1 = *reinterpret_cast<const u16x8*>(xr + 8);
  u16x8 w0 = *reinterpret_cast<const u16x8*>(wr);
  u16x8 w1 = *reinterpret_cast<const u16x8*>(wr + 8);
  float s0 = 0.f, s1 = 0.f;
#pragma unroll
  for (int j = 0; j < 8; ++j) {
    s0 = fmaf(bf2f(x0[j]), bf2f(w0[j]), s0);
    s1 = fmaf(bf2f(x1[j]), bf2f(w1[j]), s1);
  }
  float s = s0 + s1;
#pragma unroll
  for (int k = 32; k >= 1; k >>= 1) s += __shfl_xor(s, k);
  if (l == 0) {
    size_t off;
    if (bin < FBIN) off = ((size_t)bb * FBIN + bin) * NFRAMES + fr;
    else            off = TOTOUT + ((size_t)bb * FBIN + (bin - FBIN)) * NFRAMES + fr;
    out[off] = s;
  }
}

// ---- exact f32 direct kernel: fallback only ----
__global__ void stft_direct_kernel(const float* __restrict__ x, const float* __restrict__ W,
                                   float* __restrict__ out,
                                   int bin_lo, int nbins, int fr_lo, int nframes) {
  long long total = (long long)NBATCH * nbins * nframes;
  for (long long t = (long long)blockIdx.x * blockDim.x + threadIdx.x; t < total;
       t += (long long)gridDim.x * blockDim.x) {
    int fr = fr_lo + (int)(t % nframes);
    long long q = t / nframes;
    int bin = bin_lo + (int)(q % nbins);
    int b   = (int)(q / nbins);
    const float* xb = x + (long long)b * XLEN;
    const float* wrow = W + (long long)bin * NFFT;
    float s = 0.f;
    const int base = fr * HOPSZ - (NFFT / 2);
    for (int j = 0; j < NFFT; ++j) {
      int xi = base + j;
      float xv = ((unsigned)xi < (unsigned)XLEN) ? xb[xi] : 0.f;
      s = fmaf(xv, wrow[j], s);
    }
    size_t off;
    if (bin < FBIN) off = ((size_t)b * FBIN + bin) * NFRAMES + fr;
    else            off = TOTOUT + ((size_t)b * FBIN + (bin - FBIN)) * NFRAMES + fr;
    out[off] = s;
  }
}

extern "C" void kernel_launch(void* const* d_in, const int* in_sizes, int n_in,
                              void* d_out, int out_size, void* d_ws, size_t ws_size,
                              hipStream_t stream) {
  const float* x = (const float*)d_in[0];
  const float* W = (const float*)d_in[1];
  float* out = (float*)d_out;

  const size_t xp_bytes = (size_t)NBATCH * PADLEN * sizeof(unsigned short);
  const size_t wb_bytes = (size_t)NBINS2 * NFFT * sizeof(unsigned short);

  if (ws_size >= xp_bytes + wb_bytes) {
    unsigned short* xp = (unsigned short*)d_ws;
    unsigned short* wb = (unsigned short*)((char*)d_ws + xp_bytes);

    {
      long long threads = (long long)NBATCH * PADLEN / 8;
      pack_x_kernel<<<(int)((threads + 255) / 256), 256, 0, stream>>>(x, xp);
    }
    pack_w_kernel<<<(NBINS2 * NFFT / 4 + 255) / 256, 256, 0, stream>>>(W, wb);

    stft_mfma8_kernel<<<NWG, 512, LDS_BYTES, stream>>>(xp, wb, out);
    stft_tail_kernel<<<NTAIL / 8, 512, 0, stream>>>(xp, wb, out);
  } else {
    stft_direct_kernel<<<2048, 256, 0, stream>>>(x, W, out, 0, NBINS2, 0, NFRAMES);
  }
}